// Round 8
// baseline (106.153 us; speedup 1.0000x reference)
//
#include <hip/hip_runtime.h>

typedef short bf16x8 __attribute__((ext_vector_type(8)));
typedef float f32x4  __attribute__((ext_vector_type(4)));
typedef unsigned int u32x4 __attribute__((ext_vector_type(4)));

#define L_RES 1280
#define A_ATM 14
#define K_NB  30
#define FEAT  656
#define KPAD  672          // 656 padded to 21*32 for the MFMA K-loop
#define NCH   128
#define AF_STRIDE 680      // row stride 340 dwords = 20 mod 32 -> 8 start-bank classes
#define E_OUT_OFF (L_RES * K_NB * NCH)

// fp32 -> bf16 round-to-nearest-even
__device__ __forceinline__ ushort f2bf(float x) {
    union { float f; unsigned u; } v; v.f = x;
    unsigned r = (v.u + 0x7fffu + ((v.u >> 16) & 1u)) >> 16;
    return (ushort)r;
}

// W_edge [656][128] fp32  ->  Wt [128][672] bf16 (k-padded with zeros)
__global__ __launch_bounds__(256) void wt_convert_kernel(const float* __restrict__ W,
                                                         ushort* __restrict__ Wt) {
    int idx = blockIdx.x * 256 + threadIdx.x;   // n*KPAD + k
    if (idx >= NCH * KPAD) return;
    int n = idx / KPAD, k = idx - n * KPAD;
    float v = (k < FEAT) ? W[k * NCH + n] : 0.0f;
    Wt[idx] = f2bf(v);
}

__global__ __launch_bounds__(256, 3) void sidechain_feat_kernel(
    const float* __restrict__ X,
    const int*   __restrict__ ridx,
    const int*   __restrict__ clab,
    const int*   __restrict__ Eidx,
    const float* __restrict__ Wpos,
    const float* __restrict__ bpos,
    const ushort* __restrict__ Wt,     // bf16 [128][672]
    const float* __restrict__ gamma,
    const float* __restrict__ beta,
    float* __restrict__ out)
{
    __shared__ __align__(16) ushort Af[32][AF_STRIDE];   // 43,520 B
    __shared__ __align__(16) float scj[K_NB][10][3];     //  3,600 B (coalesced stage)
    __shared__ float bbs[4][3];
    __shared__ int   nbr[K_NB];
    __shared__ __align__(16) float part[32][4][2];       // per-row (sum, sumsq) per wave

    const int i = blockIdx.x;          // residue
    const int t = threadIdx.x;
    const int w = t >> 6;              // wave 0..3
    const int lane = t & 63;
    const int frow = lane & 15;
    const int quad = lane >> 4;
    const int c0 = (2 * w) * 16 + frow;    // wave's two output columns
    const int c1 = c0 + 16;

    // ---- early independent global prefetch: B chunks 0..3 + gamma/beta ----
    const ushort* B0p = Wt + (size_t)c0 * KPAD + quad * 8;
    const ushort* B1p = Wt + (size_t)c1 * KPAD + quad * 8;
    bf16x8 b0[4], b1[4];
#pragma unroll
    for (int q = 0; q < 4; ++q) {
        b0[q] = *(const bf16x8*)(B0p + q * 32);
        b1[q] = *(const bf16x8*)(B1p + q * 32);
    }
    float gg0 = gamma[c0], gg1 = gamma[c1];
    float be0 = beta[c0],  be1 = beta[c1];

    const int my_clab = clab[i];       // block-uniform (L1 broadcast)
    const int my_ridx = ridx[i];

    // ---- pre-barrier fills (all use direct Eidx loads; no LDS dependencies) ----
    if (t < 12) {
        const int perm[4] = {1, 0, 2, 3};
        int a = t / 3, c = t - a * 3;
        bbs[a][c] = X[(i * A_ATM + perm[a]) * 3 + c];
    }
    if (t < K_NB) nbr[t] = Eidx[i * K_NB + t];

    // scj stage: 900 items; e=idx/30 -> 30 consecutive lanes read 30 consecutive
    // dwords of neighbor e's sidechain atoms (coalesced 120B/edge); LDS writes linear.
    float* scjf = &scj[0][0][0];
#pragma unroll
    for (int u = 0; u < 4; ++u) {
        int idx = t + u * 256;
        if (idx < K_NB * 30) {
            int e = idx / 30;
            int r = idx - e * 30;
            int j = Eidx[i * K_NB + e];            // broadcast across 30 lanes
            scjf[idx] = X[(size_t)j * (A_ATM * 3) + 12 + r];
        }
    }

    // positional features (cols 0..15): 480 items, direct Eidx (16-lane broadcast)
#pragma unroll
    for (int u = 0; u < 2; ++u) {
        int idx = t + u * 256;
        if (idx < K_NB * 16) {
            int e = idx >> 4, c = idx & 15;
            int j = Eidx[i * K_NB + e];
            int d;
            if (my_clab == clab[j]) {
                int off = my_ridx - ridx[j] + 32;
                d = off < 0 ? 0 : (off > 64 ? 64 : off);
            } else {
                d = 65;
            }
            Af[e][c] = f2bf(Wpos[d * 16 + c] + bpos[c]);
            Af[e][FEAT + c] = 0;       // zero k-pad (NaN x Wt-pad 0 would poison C)
        }
    }
    // rows 30/31 stay garbage: they only feed discarded C rows 30/31
    __syncthreads();                     // barrier 1: scj/nbr/bbs/pos ready

    // ---- RBF features: 1200 items, EDGE-MINOR (conflict-light b128 writes, r7
    //      measured 0.94M); scj from LDS (stride 30 dwords -> 2-way = free) ----
#pragma unroll
    for (int u = 0; u < 5; ++u) {
        int idx = t + u * 256;
        if (idx < K_NB * 40) {
            int eg = idx % K_NB;         // edge (lane-consecutive -> bank spread)
            int pr = idx / K_NB;         // pair 0..39
            int ab = pr / 10, as = pr - ab * 10;
            int j = nbr[eg];
            float dx = bbs[ab][0] - scj[eg][as][0];
            float dy = bbs[ab][1] - scj[eg][as][1];
            float dz = bbs[ab][2] - scj[eg][as][2];
            float dist = sqrtf(dx * dx + dy * dy + dz * dz + 1e-6f);
            bool self = (j == i);        // AUTOREGRESSIVE: zero RBF on self edges
            unsigned pk[8];
#pragma unroll
            for (int q = 0; q < 8; ++q) {
                float m0 = 2.0f + (float)(2 * q)     * (20.0f / 15.0f);
                float m1 = 2.0f + (float)(2 * q + 1) * (20.0f / 15.0f);
                float a0 = (dist - m0) * 0.8f;
                float a1 = (dist - m1) * 0.8f;
                float r0 = self ? 0.0f : __expf(-a0 * a0);
                float r1 = self ? 0.0f : __expf(-a1 * a1);
                asm("v_cvt_pk_bf16_f32 %0, %1, %2" : "=v"(pk[q]) : "v"(r0), "v"(r1));
            }
            u32x4* dst = (u32x4*)&Af[eg][16 + pr * 16];   // 16B-aligned
            u32x4 v0 = {pk[0], pk[1], pk[2], pk[3]};
            u32x4 v1 = {pk[4], pk[5], pk[6], pk[7]};
            dst[0] = v0;
            dst[1] = v1;
        }
    }
    __syncthreads();                     // barrier 2: Af ready

    // ---- MFMA GEMM: C[32 x 128] = Af[32 x 672] @ Wt^T; A depth-2, B depth-4 ----
    // fully-unrolled loop keeps rotating-array indices compile-time (no scratch)
    const ushort* A0p = &Af[frow][quad * 8];
    const ushort* A1p = &Af[16 + frow][quad * 8];
    bf16x8 a0[2], a1[2];
#pragma unroll
    for (int q = 0; q < 2; ++q) {
        a0[q] = *(const bf16x8*)(A0p + q * 32);
        a1[q] = *(const bf16x8*)(A1p + q * 32);
    }

    f32x4 acc00 = {0.f,0.f,0.f,0.f}, acc01 = {0.f,0.f,0.f,0.f};
    f32x4 acc10 = {0.f,0.f,0.f,0.f}, acc11 = {0.f,0.f,0.f,0.f};

#pragma unroll
    for (int c = 0; c < 21; ++c) {
        bf16x8 ua0 = a0[c & 1], ua1 = a1[c & 1];
        bf16x8 ub0 = b0[c & 3], ub1 = b1[c & 3];
        if (c + 2 < 21) {                                 // depth-2 A prefetch (LDS)
            a0[c & 1] = *(const bf16x8*)(A0p + (c + 2) * 32);
            a1[c & 1] = *(const bf16x8*)(A1p + (c + 2) * 32);
        }
        if (c + 4 < 21) {                                 // depth-4 B prefetch (L2)
            b0[c & 3] = *(const bf16x8*)(B0p + (c + 4) * 32);
            b1[c & 3] = *(const bf16x8*)(B1p + (c + 4) * 32);
        }
        acc00 = __builtin_amdgcn_mfma_f32_16x16x32_bf16(ua0, ub0, acc00, 0, 0, 0);
        acc01 = __builtin_amdgcn_mfma_f32_16x16x32_bf16(ua0, ub1, acc01, 0, 0, 0);
        acc10 = __builtin_amdgcn_mfma_f32_16x16x32_bf16(ua1, ub0, acc10, 0, 0, 0);
        acc11 = __builtin_amdgcn_mfma_f32_16x16x32_bf16(ua1, ub1, acc11, 0, 0, 0);
    }

    // ---- register LayerNorm: per-wave 32-col partials via 16-lane butterfly ----
    // C/D layout (verified m89/m91): col = lane&15, row = quad*4 + reg
    float s0[4], q0[4], s1[4], q1[4];
#pragma unroll
    for (int r = 0; r < 4; ++r) {
        s0[r] = acc00[r] + acc01[r];
        q0[r] = acc00[r] * acc00[r] + acc01[r] * acc01[r];
        s1[r] = acc10[r] + acc11[r];
        q1[r] = acc10[r] * acc10[r] + acc11[r] * acc11[r];
    }
#pragma unroll
    for (int off = 1; off < 16; off <<= 1) {
#pragma unroll
        for (int r = 0; r < 4; ++r) {
            s0[r] += __shfl_xor(s0[r], off);
            q0[r] += __shfl_xor(q0[r], off);
            s1[r] += __shfl_xor(s1[r], off);
            q1[r] += __shfl_xor(q1[r], off);
        }
    }
    if (frow == 0) {
#pragma unroll
        for (int r = 0; r < 4; ++r) {
            int row = quad * 4 + r;
            part[row][w][0]      = s0[r];
            part[row][w][1]      = q0[r];
            part[16 + row][w][0] = s1[r];
            part[16 + row][w][1] = q1[r];
        }
    }
    __syncthreads();                     // barrier 3: partials ready

    // ---- finalize LN + store straight from accumulators ----
#pragma unroll
    for (int r = 0; r < 4; ++r) {
        int row = quad * 4 + r;          // 0..15, always valid
        {
            f32x4 pa = *(const f32x4*)&part[row][0][0];
            f32x4 pb = *(const f32x4*)&part[row][2][0];
            float S = pa[0] + pa[2] + pb[0] + pb[2];
            float Q = pa[1] + pa[3] + pb[1] + pb[3];
            float mean = S * (1.0f / 128.0f);
            float rstd = rsqrtf(Q * (1.0f / 128.0f) - mean * mean + 1e-5f);
            float* o = out + (size_t)(i * K_NB + row) * NCH;
            o[c0] = (acc00[r] - mean) * rstd * gg0 + be0;
            o[c1] = (acc01[r] - mean) * rstd * gg1 + be1;
        }
        int row1 = 16 + row;             // 16..31; rows 30/31 discarded
        if (row1 < K_NB) {
            f32x4 pa = *(const f32x4*)&part[row1][0][0];
            f32x4 pb = *(const f32x4*)&part[row1][2][0];
            float S = pa[0] + pa[2] + pb[0] + pb[2];
            float Q = pa[1] + pa[3] + pb[1] + pb[3];
            float mean = S * (1.0f / 128.0f);
            float rstd = rsqrtf(Q * (1.0f / 128.0f) - mean * mean + 1e-5f);
            float* o = out + (size_t)(i * K_NB + row1) * NCH;
            o[c0] = (acc10[r] - mean) * rstd * gg0 + be0;
            o[c1] = (acc11[r] - mean) * rstd * gg1 + be1;
        }
    }

    // ---- E_idx passthrough (as float) ----
    if (t < K_NB) out[E_OUT_OFF + i * K_NB + t] = (float)nbr[t];
}

extern "C" void kernel_launch(void* const* d_in, const int* in_sizes, int n_in,
                              void* d_out, int out_size, void* d_ws, size_t ws_size,
                              hipStream_t stream) {
    const float* X     = (const float*)d_in[0];
    const int*   ridx  = (const int*)  d_in[1];
    const int*   clab  = (const int*)  d_in[2];
    const int*   Eidx  = (const int*)  d_in[3];
    // d_in[4] = atom_mask (unused by reference forward)
    const float* Wpos  = (const float*)d_in[5];
    const float* bpos  = (const float*)d_in[6];
    const float* Wedge = (const float*)d_in[7];
    const float* gamma = (const float*)d_in[8];
    const float* beta  = (const float*)d_in[9];
    float* out = (float*)d_out;

    // ws poison fill is unconditional (round-1 evidence) -> using ws is free.
    ushort* Wt = (ushort*)d_ws;   // 128*672*2 = 172,032 B

    wt_convert_kernel<<<(NCH * KPAD + 255) / 256, 256, 0, stream>>>(Wedge, Wt);
    sidechain_feat_kernel<<<L_RES, 256, 0, stream>>>(
        X, ridx, clab, Eidx, Wpos, bpos, Wt, gamma, beta, out);
}